// Round 5
// baseline (78.384 us; speedup 1.0000x reference)
//
#include <hip/hip_runtime.h>

#define NROWS 16384
#define DDIM  256
#define GBLK  2048   // 8 blocks/CU x 256 CUs: all co-resident (LDS 5KB, VGPR<=64)
#define PBLK  8      // phase-B blocks, 32 columns each

// g = (X W)(X^T (X b)) via u = Xb, v = X^T u, w2 = W v, g = X w2.
// R12: fused, fence-free barriers (R4-proven). Change vs R4: phase A's 524K
// device-scope atomicAdd RMWs (~9us serialization at memory-side atomic
// units) -> unique-row atomic STOREs (write-through, no serialization);
// phase B column-split reduces p1 and contributes w2 with only 2048 RMWs.

// bars layout (uint index; one counter per 128B line = stride 32)
#define SUB1  0      // 64 lines (32 arrivals each)
#define MAIN1 2048
#define GO1   2080   // 64 lines
#define MAIN2 4128
#define GO2   4160   // 64 lines
#define REFC  6208   // untouched cell: uniform poison reference

__device__ __forceinline__ unsigned aload(const unsigned* p) {
    return __hip_atomic_load(p, __ATOMIC_RELAXED, __HIP_MEMORY_SCOPE_AGENT);
}
__device__ __forceinline__ float afload(const float* p) {
    return __hip_atomic_load(p, __ATOMIC_RELAXED, __HIP_MEMORY_SCOPE_AGENT);
}
__device__ __forceinline__ void astore(float* p, float v) {
    __hip_atomic_store(p, v, __ATOMIC_RELAXED, __HIP_MEMORY_SCOPE_AGENT);
}
__device__ __forceinline__ unsigned armw(unsigned* p) {
    return __hip_atomic_fetch_add(p, 1u, __ATOMIC_RELAXED, __HIP_MEMORY_SCOPE_AGENT);
}

__global__ __launch_bounds__(256, 8)
void fused(const float* __restrict__ X, const float* __restrict__ W,
           const float* __restrict__ b, float* __restrict__ p1,
           float* __restrict__ w2, unsigned* __restrict__ bars,
           float* __restrict__ g) {
    const int tid  = threadIdx.x;
    const int lane = tid & 63;
    const int wave = tid >> 6;
    const int bid  = blockIdx.x;

    __shared__ __align__(16) float sp[4 * DDIM];  // 4 KB scratch
    __shared__ __align__(16) float sv[DDIM];      // 1 KB

    const float4* X4 = (const float4*)X;

    unsigned initv = 0;
    if (tid == 0) initv = aload(&bars[REFC]);     // uniform ws poison pattern

    // ---- Phase A: t = x.b per row (butterfly), vacc += t*x; LDS-combine;
    //      UNIQUE partial row via atomic store (write-through, no RMW).
    {
        const float4 bf = ((const float4*)b)[lane];
        float4 vacc = make_float4(0.f, 0.f, 0.f, 0.f);
        const int row0 = bid * 8 + wave * 2;
        #pragma unroll
        for (int i = 0; i < 2; ++i) {
            const float4 xv = X4[(row0 + i) * 64 + lane];
            float t = xv.x * bf.x + xv.y * bf.y + xv.z * bf.z + xv.w * bf.w;
            #pragma unroll
            for (int off = 32; off; off >>= 1) t += __shfl_xor(t, off, 64);
            vacc.x += t * xv.x; vacc.y += t * xv.y;
            vacc.z += t * xv.z; vacc.w += t * xv.w;
        }
        ((float4*)&sp[wave * DDIM])[lane] = vacc;
        __syncthreads();
        const float s = sp[tid] + sp[DDIM + tid] + sp[2*DDIM + tid] + sp[3*DDIM + tid];
        astore(&p1[bid * DDIM + tid], s);
        if (bid == GBLK - 1) astore(&w2[tid], 0.f);   // clean base for phase-B RMWs
    }

    // ---- barrier 1: all 2048 arrive (hierarchical, fence-free)
    asm volatile("s_waitcnt vmcnt(0)" ::: "memory");
    __syncthreads();
    if (tid == 0) {
        const int grp = bid >> 5, mem = bid & 31;
        unsigned old = armw(&bars[SUB1 + grp * 32]);
        if (old - initv == 31u) armw(&bars[MAIN1]);
        unsigned spins = 0;
        if (mem == 0) {
            while (aload(&bars[MAIN1]) - initv < 64u) {
                __builtin_amdgcn_s_sleep(4);
                if (++spins > 400000u) break;          // hang-proof
            }
            __hip_atomic_store(&bars[GO1 + grp * 32], initv + 1u,
                               __ATOMIC_RELAXED, __HIP_MEMORY_SCOPE_AGENT);
        } else {
            while (aload(&bars[GO1 + grp * 32]) - initv == 0u) {
                __builtin_amdgcn_s_sleep(4);
                if (++spins > 400000u) break;
            }
        }
    }
    __syncthreads();

    // ---- Phase B (blocks 0..7): block owns cols [32*bid, 32*bid+32).
    //      Sum all 2048 p1 rows for those cols; LDS-reduce -> v-slice;
    //      contribute W[:,cols] . v[cols] with ONE atomicAdd per thread.
    if (bid < PBLK) {
        const int c   = tid & 31;            // column within slice
        const int seg = tid >> 5;            // 0..7: 256-row segment
        const float* base = p1 + (seg * 256) * DDIM + bid * 32 + c;
        float acc = 0.f;
        for (int it = 0; it < 256; it += 8) {   // manual 8-wide ILP batches
            const float t0 = afload(base + (it + 0) * DDIM);
            const float t1 = afload(base + (it + 1) * DDIM);
            const float t2 = afload(base + (it + 2) * DDIM);
            const float t3 = afload(base + (it + 3) * DDIM);
            const float t4 = afload(base + (it + 4) * DDIM);
            const float t5 = afload(base + (it + 5) * DDIM);
            const float t6 = afload(base + (it + 6) * DDIM);
            const float t7 = afload(base + (it + 7) * DDIM);
            acc += ((t0 + t1) + (t2 + t3)) + ((t4 + t5) + (t6 + t7));
        }
        sp[seg * 32 + c] = acc;
        __syncthreads();
        if (tid < 32) {
            float v = 0.f;
            #pragma unroll
            for (int s2 = 0; s2 < 8; ++s2) v += sp[s2 * 32 + tid];
            sv[tid] = v;                      // v[32*bid + tid]
        }
        __syncthreads();
        const float4* W4  = (const float4*)W;   // row stride 64 float4
        const float4* sv4 = (const float4*)sv;  // 8 float4 of v-slice
        float w2p = 0.f;
        #pragma unroll
        for (int k = 0; k < 8; ++k) {
            const float4 wv = W4[tid * 64 + bid * 8 + k];
            const float4 vv = sv4[k];
            w2p += wv.x * vv.x + wv.y * vv.y + wv.z * vv.z + wv.w * vv.w;
        }
        atomicAdd(&w2[tid], w2p);             // 2048 RMWs total over 16 lines
    }

    // ---- barrier 2: 8 producers signal, everyone waits (fence-free)
    asm volatile("s_waitcnt vmcnt(0)" ::: "memory");
    __syncthreads();
    if (tid == 0) {
        if (bid < PBLK) armw(&bars[MAIN2]);
        const int grp = bid >> 5, mem = bid & 31;
        unsigned spins = 0;
        if (mem == 0) {
            while (aload(&bars[MAIN2]) - initv < (unsigned)PBLK) {
                __builtin_amdgcn_s_sleep(4);
                if (++spins > 400000u) break;
            }
            __hip_atomic_store(&bars[GO2 + grp * 32], initv + 1u,
                               __ATOMIC_RELAXED, __HIP_MEMORY_SCOPE_AGENT);
        } else {
            while (aload(&bars[GO2 + grp * 32]) - initv == 0u) {
                __builtin_amdgcn_s_sleep(4);
                if (++spins > 400000u) break;
            }
        }
    }
    __syncthreads();

    // ---- Phase C: g = X w2 — SAME rows as phase A (L2-warm, no cache
    //      maintenance anywhere). w2 read coherently once per block.
    {
        sv[tid] = afload(&w2[tid]);
        __syncthreads();
        const float4 wf = ((const float4*)sv)[lane];
        const int row0 = bid * 8 + wave * 2;
        #pragma unroll
        for (int i = 0; i < 2; ++i) {
            const float4 xv = X4[(row0 + i) * 64 + lane];
            float t = xv.x * wf.x + xv.y * wf.y + xv.z * wf.z + xv.w * wf.w;
            #pragma unroll
            for (int off = 32; off; off >>= 1) t += __shfl_xor(t, off, 64);
            if (lane == 0) g[row0 + i] = t;
        }
    }
}

extern "C" void kernel_launch(void* const* d_in, const int* in_sizes, int n_in,
                              void* d_out, int out_size, void* d_ws, size_t ws_size,
                              hipStream_t stream) {
    const float* X = (const float*)d_in[0];   // (16384, 256)
    const float* W = (const float*)d_in[1];   // (256, 256)
    const float* b = (const float*)d_in[2];   // (256,)
    float* g = (float*)d_out;                 // (16384,)

    float*    p1   = (float*)d_ws;                     // 2048*256 floats (2 MB)
    float*    w2   = p1 + GBLK * DDIM;                 // 256 floats
    unsigned* bars = (unsigned*)d_ws + 532480;         // 64B-aligned, clear of p1/w2

    fused<<<GBLK, 256, 0, stream>>>(X, W, b, p1, w2, bars, g);
}